// Round 4
// baseline (256.449 us; speedup 1.0000x reference)
//
#include <hip/hip_runtime.h>
#include <cstdint>
#include <cstddef>

#define B_DIM 8
#define L_DIM 33600
#define N_DIM 128
#define C_DIM 80
#define K_TOP 13
#define EPS_F 1e-9f
#define CAP 4096      // per-(b,n) bucket; max plausible inside ~2600 (mean+30sigma)

// Bit-exact replica of the reference IoU (f32, no FMA contraction, same op order).
__device__ __forceinline__ float iou_pair(float g0, float g1, float g2, float g3,
                                          float p0, float p1, float p2, float p3) {
    float ltx = fmaxf(g0, p0), lty = fmaxf(g1, p1);
    float rbx = fminf(g2, p2), rby = fminf(g3, p3);
    float wx = fmaxf(__fsub_rn(rbx, ltx), 0.0f);
    float wy = fmaxf(__fsub_rn(rby, lty), 0.0f);
    float inter = __fmul_rn(wx, wy);
    float ag = __fmul_rn(__fsub_rn(g2, g0), __fsub_rn(g3, g1));
    float ap = __fmul_rn(__fsub_rn(p2, p0), __fsub_rn(p3, p1));
    float den = __fadd_rn(__fsub_rn(__fadd_rn(ag, ap), inter), EPS_F);
    float iou = __fdiv_rn(inter, den);
    if (iou > 1.0f) iou = 0.0f;            // (1.0 + 1e-9) rounds to 1.0f in f32
    iou = fminf(fmaxf(iou, 0.0f), 1.0f);
    return iou;
}

// Sortable key: (truncated double bits of s>=0) | (0xFFFF - l) in low 16.
// Larger key == (higher value, then lower anchor index). Keys are unique.
__device__ __forceinline__ unsigned long long make_key(double s, int l) {
    unsigned long long sb = (unsigned long long)__double_as_longlong(s);
    return (sb & 0xFFFFFFFFFFFF0000ull) | (unsigned long long)(0xFFFF - l);
}

// K_push: one thread per 4 anchors. Test containment vs all 128 GT boxes
// (LDS broadcast, amortized over 4 anchors), accumulate 128-bit masks in
// registers, then scatter-push inside pairs (l>=32) into per-(b,n) buckets.
__global__ __launch_bounds__(256) void k_push(
    const float* __restrict__ pts, const float* __restrict__ gbox,
    const float* __restrict__ gpad,
    int* __restrict__ cnt, unsigned short* __restrict__ bucket)
{
    const int b = blockIdx.y, t = threadIdx.x;
    __shared__ float4 gb[N_DIM];
    __shared__ float  gp[N_DIM];
    if (t < N_DIM) {
        gb[t] = reinterpret_cast<const float4*>(gbox)[(size_t)b * N_DIM + t];
        gp[t] = gpad[b * N_DIM + t];
    }
    __syncthreads();

    const int q = blockIdx.x * 256 + t;        // anchor-quad index
    const int l0 = q * 4;
    if (l0 >= L_DIM) return;                   // 8400 quads exactly; tail threads idle

    const float4 p01 = reinterpret_cast<const float4*>(pts)[2 * q];
    const float4 p23 = reinterpret_cast<const float4*>(pts)[2 * q + 1];
    const float ax[4] = {p01.x, p01.z, p23.x, p23.z};
    const float ay[4] = {p01.y, p01.w, p23.y, p23.w};

    unsigned long long m0[4] = {0, 0, 0, 0}, m1[4] = {0, 0, 0, 0};
    for (int n = 0; n < N_DIM; ++n) {
        if (gp[n] <= 0.0f) continue;           // wave-uniform skip of padded GTs
        const float4 g = gb[n];
        #pragma unroll
        for (int a = 0; a < 4; ++a) {
            bool in = (ax[a] >= g.x && ax[a] <= g.z && ay[a] >= g.y && ay[a] <= g.w);
            if (n < 64) m0[a] |= in ? (1ull << n) : 0ull;
            else        m1[a] |= in ? (1ull << (n - 64)) : 0ull;
        }
    }

    #pragma unroll
    for (int a = 0; a < 4; ++a) {
        const int l = l0 + a;
        if (l < 32) continue;                  // 0..31 are unconditional seeds downstream
        unsigned long long m = m0[a];
        while (m) {
            int n = __ffsll((long long)m) - 1; m &= m - 1;
            int bn = b * N_DIM + n;
            int pos = atomicAdd(&cnt[bn], 1);
            if (pos < CAP) bucket[(size_t)bn * CAP + pos] = (unsigned short)l;
        }
        m = m1[a];
        while (m) {
            int n = __ffsll((long long)m) - 1; m &= m - 1;
            int bn = b * N_DIM + (n + 64);
            int pos = atomicAdd(&cnt[bn], 1);
            if (pos < CAP) bucket[(size_t)bn * CAP + pos] = (unsigned short)l;
        }
    }
}

// K_top13: one 256-thread block per (gt n, batch b). Score 32 seeds + bucket
// candidates, per-thread 13-deep sorted reg list, per-wave shuffle head-merge,
// one barrier, single-wave final merge of 4x13 heads; atomicOr posbits.
__global__ __launch_bounds__(256) void k_top13(
    const float* __restrict__ psc, const float* __restrict__ pbox,
    const float* __restrict__ pts, const int* __restrict__ glbl,
    const float* __restrict__ gbox, const float* __restrict__ gpad,
    const int* __restrict__ cnt, const unsigned short* __restrict__ bucket,
    unsigned long long* __restrict__ posbits)
{
    const int n = blockIdx.x, b = blockIdx.y, t = threadIdx.x;
    if (gpad[b * N_DIM + n] <= 0.0f) return;   // padded GT: uniform block exit

    const float g0 = gbox[(b * N_DIM + n) * 4 + 0];
    const float g1 = gbox[(b * N_DIM + n) * 4 + 1];
    const float g2 = gbox[(b * N_DIM + n) * 4 + 2];
    const float g3 = gbox[(b * N_DIM + n) * 4 + 3];
    int lbl = glbl[b * N_DIM + n];
    lbl = min(max(lbl, 0), C_DIM - 1);
    const float* psb = psc + (size_t)b * L_DIM * C_DIM;
    const float* pbb = pbox + (size_t)b * L_DIM * 4;
    const int bn = b * N_DIM + n;
    const int nc = min(cnt[bn], CAP);

    // per-thread top-13, sorted desc, registers only (guarded unrolled insert)
    unsigned long long key[K_TOP];
    #pragma unroll
    for (int k = 0; k < K_TOP; ++k) key[k] = 0ull;

    for (int i = t; i < nc + 32; i += 256) {
        const int l = (i < 32) ? i : (int)bucket[(size_t)bn * CAP + (i - 32)];
        const float2 ap = reinterpret_cast<const float2*>(pts)[l];
        unsigned long long ck = (unsigned long long)(0xFFFF - l);  // s == 0
        if (ap.x >= g0 && ap.x <= g2 && ap.y >= g1 && ap.y <= g3) {
            const float4 pbv = reinterpret_cast<const float4*>(pbb)[l];
            float iou = iou_pair(g0, g1, g2, g3, pbv.x, pbv.y, pbv.z, pbv.w);
            if (iou > 0.0f) {
                float cs = psb[(size_t)l * C_DIM + lbl];
                double d = (double)iou, d2 = d * d;
                ck = make_key((double)cs * (d2 * d2 * d2), l);
            }
        }
        if (ck > key[K_TOP - 1]) {
            #pragma unroll
            for (int k = 0; k < K_TOP; ++k) {
                unsigned long long hi = key[k] > ck ? key[k] : ck;
                unsigned long long lo = key[k] > ck ? ck : key[k];
                key[k] = hi; ck = lo;
            }
        }
    }

    // per-wave head-merge (4 waves), no barriers
    const int lane = t & 63, wid = t >> 6;
    __shared__ unsigned long long wl[4 * K_TOP];
    #pragma unroll 1
    for (int r = 0; r < K_TOP; ++r) {
        unsigned long long best = key[0];
        #pragma unroll
        for (int d = 1; d < 64; d <<= 1) {
            unsigned long long o = __shfl_xor(best, d, 64);
            best = o > best ? o : best;
        }
        if (key[0] == best && best != 0ull) {  // unique keys -> one winner
            #pragma unroll
            for (int k = 0; k < K_TOP - 1; ++k) key[k] = key[k + 1];
            key[K_TOP - 1] = 0ull;
        }
        if (lane == 0) wl[wid * K_TOP + r] = best;
    }
    __syncthreads();
    if (wid != 0) return;

    // single-wave final merge of 52 heads (1 per lane)
    unsigned long long v = (lane < 4 * K_TOP) ? wl[lane] : 0ull;
    #pragma unroll 1
    for (int r = 0; r < K_TOP; ++r) {
        unsigned long long best = v;
        #pragma unroll
        for (int d = 1; d < 64; d <<= 1) {
            unsigned long long o = __shfl_xor(best, d, 64);
            best = o > best ? o : best;
        }
        if (v == best) v = 0ull;               // winner removed (keys unique, best>0)
        if (lane == 0) {
            int win = 0xFFFF - (int)(best & 0xFFFFull);
            atomicOr(&posbits[((size_t)b * L_DIM + win) * 2 + (n >> 6)],
                     1ULL << (n & 63));
        }
    }
}

// K2: one thread per anchor. Recompute 128 ious (GT boxes in LDS), build
// positive = topk_bit & spatial, resolve conflicts via best-iou argmax
// (first-max semantics), write labels/boxes, feed per-GT maxima atomics.
__global__ __launch_bounds__(256) void k_assign(
    const float* __restrict__ psc, const float* __restrict__ pbox,
    const float* __restrict__ pts, const int* __restrict__ glbl,
    const float* __restrict__ gbox,
    const unsigned long long* __restrict__ posbits,
    const int* __restrict__ bgp,
    float* __restrict__ out_lab, float* __restrict__ out_box,
    int* __restrict__ fin_out, float* __restrict__ alat,
    float* __restrict__ maxal, float* __restrict__ maxio)
{
    const int b = blockIdx.y, t = threadIdx.x;
    const int l = blockIdx.x * 256 + t;
    __shared__ float4 gb[N_DIM];
    __shared__ int    gl[N_DIM];
    if (t < N_DIM) {
        gb[t] = reinterpret_cast<const float4*>(gbox)[(size_t)b * N_DIM + t];
        gl[t] = glbl[b * N_DIM + t];
    }
    __syncthreads();
    if (l >= L_DIM) return;

    const size_t bl = (size_t)b * L_DIM + l;
    const float4 pb = reinterpret_cast<const float4*>(pbox)[bl];
    const float2 ap = reinterpret_cast<const float2*>(pts)[l];
    const unsigned long long w0 = posbits[bl * 2 + 0];
    const unsigned long long w1 = posbits[bl * 2 + 1];

    unsigned long long s0 = 0ull, s1 = 0ull;
    float best = -1.0f; int bestn = 0;
    for (int n = 0; n < N_DIM; ++n) {
        float4 g = gb[n];
        float iou = iou_pair(g.x, g.y, g.z, g.w, pb.x, pb.y, pb.z, pb.w);
        if (iou > best) { best = iou; bestn = n; }            // strict > = first-max
        if (ap.x >= g.x && ap.x <= g.z && ap.y >= g.y && ap.y <= g.w) {
            if (n < 64) s0 |= 1ull << n; else s1 |= 1ull << (n - 64);
        }
    }
    unsigned long long p0 = w0 & s0, p1 = w1 & s1;
    int pcnt = __popcll(p0) + __popcll(p1);
    int fin;
    if (pcnt == 0) fin = -1;
    else if (pcnt == 1) fin = p0 ? (__ffsll(p0) - 1) : (64 + __ffsll(p1) - 1);
    else {
        bool posbest = (bestn < 64) ? ((p0 >> bestn) & 1ull) : ((p1 >> (bestn - 64)) & 1ull);
        fin = posbest ? bestn : -1;
    }

    out_lab[bl] = (fin >= 0) ? (float)gl[fin] : (float)bgp[0];
    int gidx = (fin >= 0) ? fin : 0;              // ref gathers boxes with argmax=0 for bg
    reinterpret_cast<float4*>(out_box)[bl] = gb[gidx];
    fin_out[bl] = fin;

    if (fin >= 0) {
        float4 g = gb[fin];
        float iou = iou_pair(g.x, g.y, g.z, g.w, pb.x, pb.y, pb.z, pb.w);
        int lb = min(max(gl[fin], 0), C_DIM - 1);
        float cs = psc[bl * C_DIM + lb];
        float al = cs * powf(iou, 6.0f);
        alat[bl] = al;
        // all values >= 0, init 0 -> int-compare == float-compare
        atomicMax((int*)&maxal[b * N_DIM + fin], __float_as_int(al));
        atomicMax((int*)&maxio[b * N_DIM + fin], __float_as_int(iou));
    }
}

// K_out: fused norm + one-hot score fill. 16 anchors per block: threads 0..15
// compute nf/cls into LDS, then 320 coalesced float4 stores (C=80 -> 20/anchor).
__global__ __launch_bounds__(256) void k_out(
    const int* __restrict__ fin_out, const float* __restrict__ alat,
    const float* __restrict__ maxal, const float* __restrict__ maxio,
    const int* __restrict__ glbl,
    float* __restrict__ outs)
{
    const int APB = 16;
    const int a0 = blockIdx.x * APB;
    const int t = threadIdx.x;
    __shared__ float snf[APB];
    __shared__ int   scl[APB];
    if (t < APB) {
        int a = a0 + t;
        float v = 0.0f; int c = -1;
        if (a < B_DIM * L_DIM) {
            int b = a / L_DIM;
            int fin = fin_out[a];
            if (fin >= 0) {
                v = alat[a] / (maxal[b * N_DIM + fin] + EPS_F) * maxio[b * N_DIM + fin];
                c = glbl[b * N_DIM + fin];
            }
        }
        snf[t] = v; scl[t] = c;
    }
    __syncthreads();
    float4* out4 = reinterpret_cast<float4*>(outs);
    for (int j = t; j < APB * 20; j += 256) {
        int ai = j / 20;                      // anchor within block
        int a = a0 + ai;
        if (a >= B_DIM * L_DIM) continue;
        int c0 = (j - ai * 20) * 4;
        float v = snf[ai]; int cl = scl[ai];
        float4 o;
        o.x = (c0 + 0 == cl) ? v : 0.0f;
        o.y = (c0 + 1 == cl) ? v : 0.0f;
        o.z = (c0 + 2 == cl) ? v : 0.0f;
        o.w = (c0 + 3 == cl) ? v : 0.0f;
        out4[(size_t)a * 20 + (j - ai * 20)] = o;
    }
}

extern "C" void kernel_launch(void* const* d_in, const int* in_sizes, int n_in,
                              void* d_out, int out_size, void* d_ws, size_t ws_size,
                              hipStream_t stream)
{
    const float* psc  = (const float*)d_in[0];   // [B,L,C]
    const float* pbox = (const float*)d_in[1];   // [B,L,4]
    const float* pts  = (const float*)d_in[2];   // [1,L,2]
    const int*   glbl = (const int*)d_in[3];     // [B,N,1]
    const float* gbox = (const float*)d_in[4];   // [B,N,4]
    const float* gpad = (const float*)d_in[5];   // [B,N,1]
    const int*   bgp  = (const int*)d_in[6];     // scalar (=C)

    // workspace layout (8-byte aligned blocks)
    const size_t POSB_BYTES = (size_t)B_DIM * L_DIM * 2 * sizeof(unsigned long long); // 4,300,800
    char* w = (char*)d_ws;
    unsigned long long* posbits = (unsigned long long*)w;
    float* maxal = (float*)(w + POSB_BYTES);                                   // 4096 B
    float* maxio = (float*)(w + POSB_BYTES + 4096);                            // 4096 B
    int*   cnt   = (int*)  (w + POSB_BYTES + 8192);                            // 4096 B
    int*   fin   = (int*)  (w + POSB_BYTES + 12288);                           // 1,075,200 B
    float* alat  = (float*)(w + POSB_BYTES + 12288 + 1075200);                 // 1,075,200 B
    unsigned short* bucket = (unsigned short*)(w + POSB_BYTES + 12288 + 2 * 1075200); // 8 MB

    // zero the accumulated regions (posbits + maxal + maxio + cnt) every call
    hipMemsetAsync(d_ws, 0, POSB_BYTES + 12288, stream);

    float* out_lab = (float*)d_out;                              // [B,L]
    float* out_box = out_lab + (size_t)B_DIM * L_DIM;            // [B,L,4]
    float* out_sc  = out_box + (size_t)B_DIM * L_DIM * 4;        // [B,L,C]

    k_push<<<dim3((L_DIM / 4 + 255) / 256, B_DIM), dim3(256), 0, stream>>>(
        pts, gbox, gpad, cnt, bucket);
    k_top13<<<dim3(N_DIM, B_DIM), dim3(256), 0, stream>>>(
        psc, pbox, pts, glbl, gbox, gpad, cnt, bucket, posbits);
    k_assign<<<dim3((L_DIM + 255) / 256, B_DIM), dim3(256), 0, stream>>>(
        psc, pbox, pts, glbl, gbox, posbits, bgp,
        out_lab, out_box, fin, alat, maxal, maxio);
    k_out<<<dim3((B_DIM * L_DIM + 15) / 16), dim3(256), 0, stream>>>(
        fin, alat, maxal, maxio, glbl, out_sc);
}

// Round 5
// 140.928 us; speedup vs baseline: 1.8197x; 1.8197x over previous
//
#include <hip/hip_runtime.h>
#include <cstdint>
#include <cstddef>

#define B_DIM 8
#define L_DIM 33600
#define N_DIM 128
#define C_DIM 80
#define K_TOP 13
#define EPS_F 1e-9f
#define CAP 4096      // per-(b,n) bucket; max plausible inside ~2600 (mean+30sigma)

// Bit-exact replica of the reference IoU (f32, no FMA contraction, same op order).
__device__ __forceinline__ float iou_pair(float g0, float g1, float g2, float g3,
                                          float p0, float p1, float p2, float p3) {
    float ltx = fmaxf(g0, p0), lty = fmaxf(g1, p1);
    float rbx = fminf(g2, p2), rby = fminf(g3, p3);
    float wx = fmaxf(__fsub_rn(rbx, ltx), 0.0f);
    float wy = fmaxf(__fsub_rn(rby, lty), 0.0f);
    float inter = __fmul_rn(wx, wy);
    float ag = __fmul_rn(__fsub_rn(g2, g0), __fsub_rn(g3, g1));
    float ap = __fmul_rn(__fsub_rn(p2, p0), __fsub_rn(p3, p1));
    float den = __fadd_rn(__fsub_rn(__fadd_rn(ag, ap), inter), EPS_F);
    float iou = __fdiv_rn(inter, den);
    if (iou > 1.0f) iou = 0.0f;            // (1.0 + 1e-9) rounds to 1.0f in f32
    iou = fminf(fmaxf(iou, 0.0f), 1.0f);
    return iou;
}

// Sortable key: (truncated double bits of s>=0) | (0xFFFF - l) in low 16.
// Larger key == (higher value, then lower anchor index). Keys are unique.
__device__ __forceinline__ unsigned long long make_key(double s, int l) {
    unsigned long long sb = (unsigned long long)__double_as_longlong(s);
    return (sb & 0xFFFFFFFFFFFF0000ull) | (unsigned long long)(0xFFFF - l);
}

// K_push: one thread per anchor. Containment masks vs 128 GTs (LDS broadcast),
// then LDS-aggregated two-phase scatter:
//   A) count hits per GT in LDS (atomicAdd, no dependence on return value)
//   B) 128 threads reserve global bucket ranges (1 global atomic per (block,n))
//   C) re-walk register masks, write pairs at gbase[n] + local offset.
// Bucket order is nondeterministic; downstream top-k is order-independent.
__global__ __launch_bounds__(256) void k_push(
    const float* __restrict__ pts, const float* __restrict__ gbox,
    const float* __restrict__ gpad,
    int* __restrict__ cnt, unsigned short* __restrict__ bucket)
{
    const int b = blockIdx.y, t = threadIdx.x;
    __shared__ float4 gb[N_DIM];
    __shared__ float  gp[N_DIM];
    __shared__ int    lcnt[N_DIM];
    __shared__ int    gbase[N_DIM];
    if (t < N_DIM) {
        gb[t] = reinterpret_cast<const float4*>(gbox)[(size_t)b * N_DIM + t];
        gp[t] = gpad[b * N_DIM + t];
        lcnt[t] = 0;
    }
    __syncthreads();

    const int l = blockIdx.x * 256 + t;
    const bool active = (l >= 32 && l < L_DIM);   // l<32 are unconditional seeds downstream

    unsigned long long m0 = 0ull, m1 = 0ull;
    if (active) {
        const float2 ap = reinterpret_cast<const float2*>(pts)[l];
        for (int n = 0; n < N_DIM; ++n) {
            if (gp[n] <= 0.0f) continue;          // block-uniform skip of padded GTs
            const float4 g = gb[n];
            bool in = (ap.x >= g.x && ap.x <= g.z && ap.y >= g.y && ap.y <= g.w);
            if (n < 64) m0 |= in ? (1ull << n) : 0ull;
            else        m1 |= in ? (1ull << (n - 64)) : 0ull;
        }
        // Phase A: local counts (no return-value dependence)
        unsigned long long m = m0;
        while (m) { int n = __ffsll((long long)m) - 1; m &= m - 1; atomicAdd(&lcnt[n], 1); }
        m = m1;
        while (m) { int n = __ffsll((long long)m) - 1; m &= m - 1; atomicAdd(&lcnt[n + 64], 1); }
    }
    __syncthreads();

    // Phase B: one global reservation per (block, n); reuse lcnt as local offset
    if (t < N_DIM) {
        int c = lcnt[t];
        gbase[t] = (c > 0) ? atomicAdd(&cnt[b * N_DIM + t], c) : 0;
        lcnt[t] = 0;
    }
    __syncthreads();

    // Phase C: write pairs at reserved positions
    if (active) {
        unsigned long long m = m0;
        while (m) {
            int n = __ffsll((long long)m) - 1; m &= m - 1;
            int pos = gbase[n] + atomicAdd(&lcnt[n], 1);
            if (pos < CAP) bucket[(size_t)(b * N_DIM + n) * CAP + pos] = (unsigned short)l;
        }
        m = m1;
        while (m) {
            int n = __ffsll((long long)m) - 1; m &= m - 1;
            int pos = gbase[n + 64] + atomicAdd(&lcnt[n + 64], 1);
            if (pos < CAP) bucket[(size_t)(b * N_DIM + n + 64) * CAP + pos] = (unsigned short)l;
        }
    }
}

// K_top13: one 256-thread block per (gt n, batch b). Score 32 seeds + bucket
// candidates, per-thread 13-deep sorted reg list, per-wave shuffle head-merge,
// one barrier, single-wave final merge of 4x13 heads; atomicOr posbits.
__global__ __launch_bounds__(256) void k_top13(
    const float* __restrict__ psc, const float* __restrict__ pbox,
    const float* __restrict__ pts, const int* __restrict__ glbl,
    const float* __restrict__ gbox, const float* __restrict__ gpad,
    const int* __restrict__ cnt, const unsigned short* __restrict__ bucket,
    unsigned long long* __restrict__ posbits)
{
    const int n = blockIdx.x, b = blockIdx.y, t = threadIdx.x;
    if (gpad[b * N_DIM + n] <= 0.0f) return;   // padded GT: uniform block exit

    const float g0 = gbox[(b * N_DIM + n) * 4 + 0];
    const float g1 = gbox[(b * N_DIM + n) * 4 + 1];
    const float g2 = gbox[(b * N_DIM + n) * 4 + 2];
    const float g3 = gbox[(b * N_DIM + n) * 4 + 3];
    int lbl = glbl[b * N_DIM + n];
    lbl = min(max(lbl, 0), C_DIM - 1);
    const float* psb = psc + (size_t)b * L_DIM * C_DIM;
    const float* pbb = pbox + (size_t)b * L_DIM * 4;
    const int bn = b * N_DIM + n;
    const int nc = min(cnt[bn], CAP);

    // per-thread top-13, sorted desc, registers only (guarded unrolled insert)
    unsigned long long key[K_TOP];
    #pragma unroll
    for (int k = 0; k < K_TOP; ++k) key[k] = 0ull;

    for (int i = t; i < nc + 32; i += 256) {
        const int l = (i < 32) ? i : (int)bucket[(size_t)bn * CAP + (i - 32)];
        const float2 ap = reinterpret_cast<const float2*>(pts)[l];
        unsigned long long ck = (unsigned long long)(0xFFFF - l);  // s == 0
        if (ap.x >= g0 && ap.x <= g2 && ap.y >= g1 && ap.y <= g3) {
            const float4 pbv = reinterpret_cast<const float4*>(pbb)[l];
            float iou = iou_pair(g0, g1, g2, g3, pbv.x, pbv.y, pbv.z, pbv.w);
            if (iou > 0.0f) {
                float cs = psb[(size_t)l * C_DIM + lbl];
                double d = (double)iou, d2 = d * d;
                ck = make_key((double)cs * (d2 * d2 * d2), l);
            }
        }
        if (ck > key[K_TOP - 1]) {
            #pragma unroll
            for (int k = 0; k < K_TOP; ++k) {
                unsigned long long hi = key[k] > ck ? key[k] : ck;
                unsigned long long lo = key[k] > ck ? ck : key[k];
                key[k] = hi; ck = lo;
            }
        }
    }

    // per-wave head-merge (4 waves), no barriers
    const int lane = t & 63, wid = t >> 6;
    __shared__ unsigned long long wl[4 * K_TOP];
    #pragma unroll 1
    for (int r = 0; r < K_TOP; ++r) {
        unsigned long long best = key[0];
        #pragma unroll
        for (int d = 1; d < 64; d <<= 1) {
            unsigned long long o = __shfl_xor(best, d, 64);
            best = o > best ? o : best;
        }
        if (key[0] == best && best != 0ull) {  // unique keys -> one winner
            #pragma unroll
            for (int k = 0; k < K_TOP - 1; ++k) key[k] = key[k + 1];
            key[K_TOP - 1] = 0ull;
        }
        if (lane == 0) wl[wid * K_TOP + r] = best;
    }
    __syncthreads();
    if (wid != 0) return;

    // single-wave final merge of 52 heads (1 per lane)
    unsigned long long v = (lane < 4 * K_TOP) ? wl[lane] : 0ull;
    #pragma unroll 1
    for (int r = 0; r < K_TOP; ++r) {
        unsigned long long best = v;
        #pragma unroll
        for (int d = 1; d < 64; d <<= 1) {
            unsigned long long o = __shfl_xor(best, d, 64);
            best = o > best ? o : best;
        }
        if (v == best) v = 0ull;               // winner removed (keys unique, best>0)
        if (lane == 0) {
            int win = 0xFFFF - (int)(best & 0xFFFFull);
            atomicOr(&posbits[((size_t)b * L_DIM + win) * 2 + (n >> 6)],
                     1ULL << (n & 63));
        }
    }
}

// K2: one thread per anchor. Recompute 128 ious (GT boxes in LDS), build
// positive = topk_bit & spatial, resolve conflicts via best-iou argmax
// (first-max semantics), write labels/boxes, feed per-GT maxima atomics.
__global__ __launch_bounds__(256) void k_assign(
    const float* __restrict__ psc, const float* __restrict__ pbox,
    const float* __restrict__ pts, const int* __restrict__ glbl,
    const float* __restrict__ gbox,
    const unsigned long long* __restrict__ posbits,
    const int* __restrict__ bgp,
    float* __restrict__ out_lab, float* __restrict__ out_box,
    int* __restrict__ fin_out, float* __restrict__ alat,
    float* __restrict__ maxal, float* __restrict__ maxio)
{
    const int b = blockIdx.y, t = threadIdx.x;
    const int l = blockIdx.x * 256 + t;
    __shared__ float4 gb[N_DIM];
    __shared__ int    gl[N_DIM];
    if (t < N_DIM) {
        gb[t] = reinterpret_cast<const float4*>(gbox)[(size_t)b * N_DIM + t];
        gl[t] = glbl[b * N_DIM + t];
    }
    __syncthreads();
    if (l >= L_DIM) return;

    const size_t bl = (size_t)b * L_DIM + l;
    const float4 pb = reinterpret_cast<const float4*>(pbox)[bl];
    const float2 ap = reinterpret_cast<const float2*>(pts)[l];
    const unsigned long long w0 = posbits[bl * 2 + 0];
    const unsigned long long w1 = posbits[bl * 2 + 1];

    unsigned long long s0 = 0ull, s1 = 0ull;
    float best = -1.0f; int bestn = 0;
    for (int n = 0; n < N_DIM; ++n) {
        float4 g = gb[n];
        float iou = iou_pair(g.x, g.y, g.z, g.w, pb.x, pb.y, pb.z, pb.w);
        if (iou > best) { best = iou; bestn = n; }            // strict > = first-max
        if (ap.x >= g.x && ap.x <= g.z && ap.y >= g.y && ap.y <= g.w) {
            if (n < 64) s0 |= 1ull << n; else s1 |= 1ull << (n - 64);
        }
    }
    unsigned long long p0 = w0 & s0, p1 = w1 & s1;
    int pcnt = __popcll(p0) + __popcll(p1);
    int fin;
    if (pcnt == 0) fin = -1;
    else if (pcnt == 1) fin = p0 ? (__ffsll(p0) - 1) : (64 + __ffsll(p1) - 1);
    else {
        bool posbest = (bestn < 64) ? ((p0 >> bestn) & 1ull) : ((p1 >> (bestn - 64)) & 1ull);
        fin = posbest ? bestn : -1;
    }

    out_lab[bl] = (fin >= 0) ? (float)gl[fin] : (float)bgp[0];
    int gidx = (fin >= 0) ? fin : 0;              // ref gathers boxes with argmax=0 for bg
    reinterpret_cast<float4*>(out_box)[bl] = gb[gidx];
    fin_out[bl] = fin;

    if (fin >= 0) {
        float4 g = gb[fin];
        float iou = iou_pair(g.x, g.y, g.z, g.w, pb.x, pb.y, pb.z, pb.w);
        int lb = min(max(gl[fin], 0), C_DIM - 1);
        float cs = psc[bl * C_DIM + lb];
        float al = cs * powf(iou, 6.0f);
        alat[bl] = al;
        // all values >= 0, init 0 -> int-compare == float-compare
        atomicMax((int*)&maxal[b * N_DIM + fin], __float_as_int(al));
        atomicMax((int*)&maxio[b * N_DIM + fin], __float_as_int(iou));
    }
}

// K_out: fused norm + one-hot score fill. 16 anchors per block: threads 0..15
// compute nf/cls into LDS, then 320 coalesced float4 stores (C=80 -> 20/anchor).
__global__ __launch_bounds__(256) void k_out(
    const int* __restrict__ fin_out, const float* __restrict__ alat,
    const float* __restrict__ maxal, const float* __restrict__ maxio,
    const int* __restrict__ glbl,
    float* __restrict__ outs)
{
    const int APB = 16;
    const int a0 = blockIdx.x * APB;
    const int t = threadIdx.x;
    __shared__ float snf[APB];
    __shared__ int   scl[APB];
    if (t < APB) {
        int a = a0 + t;
        float v = 0.0f; int c = -1;
        if (a < B_DIM * L_DIM) {
            int b = a / L_DIM;
            int fin = fin_out[a];
            if (fin >= 0) {
                v = alat[a] / (maxal[b * N_DIM + fin] + EPS_F) * maxio[b * N_DIM + fin];
                c = glbl[b * N_DIM + fin];
            }
        }
        snf[t] = v; scl[t] = c;
    }
    __syncthreads();
    float4* out4 = reinterpret_cast<float4*>(outs);
    for (int j = t; j < APB * 20; j += 256) {
        int ai = j / 20;                      // anchor within block
        int a = a0 + ai;
        if (a >= B_DIM * L_DIM) continue;
        int c0 = (j - ai * 20) * 4;
        float v = snf[ai]; int cl = scl[ai];
        float4 o;
        o.x = (c0 + 0 == cl) ? v : 0.0f;
        o.y = (c0 + 1 == cl) ? v : 0.0f;
        o.z = (c0 + 2 == cl) ? v : 0.0f;
        o.w = (c0 + 3 == cl) ? v : 0.0f;
        out4[(size_t)a * 20 + (j - ai * 20)] = o;
    }
}

extern "C" void kernel_launch(void* const* d_in, const int* in_sizes, int n_in,
                              void* d_out, int out_size, void* d_ws, size_t ws_size,
                              hipStream_t stream)
{
    const float* psc  = (const float*)d_in[0];   // [B,L,C]
    const float* pbox = (const float*)d_in[1];   // [B,L,4]
    const float* pts  = (const float*)d_in[2];   // [1,L,2]
    const int*   glbl = (const int*)d_in[3];     // [B,N,1]
    const float* gbox = (const float*)d_in[4];   // [B,N,4]
    const float* gpad = (const float*)d_in[5];   // [B,N,1]
    const int*   bgp  = (const int*)d_in[6];     // scalar (=C)

    // workspace layout (8-byte aligned blocks)
    const size_t POSB_BYTES = (size_t)B_DIM * L_DIM * 2 * sizeof(unsigned long long); // 4,300,800
    char* w = (char*)d_ws;
    unsigned long long* posbits = (unsigned long long*)w;
    float* maxal = (float*)(w + POSB_BYTES);                                   // 4096 B
    float* maxio = (float*)(w + POSB_BYTES + 4096);                            // 4096 B
    int*   cnt   = (int*)  (w + POSB_BYTES + 8192);                            // 4096 B
    int*   fin   = (int*)  (w + POSB_BYTES + 12288);                           // 1,075,200 B
    float* alat  = (float*)(w + POSB_BYTES + 12288 + 1075200);                 // 1,075,200 B
    unsigned short* bucket = (unsigned short*)(w + POSB_BYTES + 12288 + 2 * 1075200); // 8 MB

    // zero the accumulated regions (posbits + maxal + maxio + cnt) every call
    hipMemsetAsync(d_ws, 0, POSB_BYTES + 12288, stream);

    float* out_lab = (float*)d_out;                              // [B,L]
    float* out_box = out_lab + (size_t)B_DIM * L_DIM;            // [B,L,4]
    float* out_sc  = out_box + (size_t)B_DIM * L_DIM * 4;        // [B,L,C]

    k_push<<<dim3((L_DIM + 255) / 256, B_DIM), dim3(256), 0, stream>>>(
        pts, gbox, gpad, cnt, bucket);
    k_top13<<<dim3(N_DIM, B_DIM), dim3(256), 0, stream>>>(
        psc, pbox, pts, glbl, gbox, gpad, cnt, bucket, posbits);
    k_assign<<<dim3((L_DIM + 255) / 256, B_DIM), dim3(256), 0, stream>>>(
        psc, pbox, pts, glbl, gbox, posbits, bgp,
        out_lab, out_box, fin, alat, maxal, maxio);
    k_out<<<dim3((B_DIM * L_DIM + 15) / 16), dim3(256), 0, stream>>>(
        fin, alat, maxal, maxio, glbl, out_sc);
}

// Round 6
// 125.659 us; speedup vs baseline: 2.0408x; 1.1215x over previous
//
#include <hip/hip_runtime.h>
#include <cstdint>
#include <cstddef>

#define B_DIM 8
#define L_DIM 33600
#define N_DIM 128
#define C_DIM 80
#define K_TOP 13
#define EPS_F 1e-9f
#define CAP 4096      // per-(b,n) bucket; max plausible inside ~2600 (mean+30sigma)

// Bit-exact replica of the reference IoU (f32, no FMA contraction, same op order).
__device__ __forceinline__ float iou_pair(float g0, float g1, float g2, float g3,
                                          float p0, float p1, float p2, float p3) {
    float ltx = fmaxf(g0, p0), lty = fmaxf(g1, p1);
    float rbx = fminf(g2, p2), rby = fminf(g3, p3);
    float wx = fmaxf(__fsub_rn(rbx, ltx), 0.0f);
    float wy = fmaxf(__fsub_rn(rby, lty), 0.0f);
    float inter = __fmul_rn(wx, wy);
    float ag = __fmul_rn(__fsub_rn(g2, g0), __fsub_rn(g3, g1));
    float ap = __fmul_rn(__fsub_rn(p2, p0), __fsub_rn(p3, p1));
    float den = __fadd_rn(__fsub_rn(__fadd_rn(ag, ap), inter), EPS_F);
    float iou = __fdiv_rn(inter, den);
    if (iou > 1.0f) iou = 0.0f;            // (1.0 + 1e-9) rounds to 1.0f in f32
    iou = fminf(fmaxf(iou, 0.0f), 1.0f);
    return iou;
}

// Sortable key: (truncated double bits of s>=0) | (0xFFFF - l) in low 16.
// Larger key == (higher value, then lower anchor index). Keys are unique.
__device__ __forceinline__ unsigned long long make_key(double s, int l) {
    unsigned long long sb = (unsigned long long)__double_as_longlong(s);
    return (sb & 0xFFFFFFFFFFFF0000ull) | (unsigned long long)(0xFFFF - l);
}

// K_push: one thread per anchor. Containment masks vs 128 GTs (LDS broadcast);
// mask stored per anchor (consumed by k_assign), then LDS-aggregated two-phase
// bucket scatter (l>=32 only; l<32 are unconditional seeds downstream).
__global__ __launch_bounds__(256) void k_push(
    const float* __restrict__ pts, const float* __restrict__ gbox,
    const float* __restrict__ gpad,
    int* __restrict__ cnt, unsigned short* __restrict__ bucket,
    ulonglong2* __restrict__ spat)
{
    const int b = blockIdx.y, t = threadIdx.x;
    __shared__ float4 gb[N_DIM];
    __shared__ float  gp[N_DIM];
    __shared__ int    lcnt[N_DIM];
    __shared__ int    gbase[N_DIM];
    if (t < N_DIM) {
        gb[t] = reinterpret_cast<const float4*>(gbox)[(size_t)b * N_DIM + t];
        gp[t] = gpad[b * N_DIM + t];
        lcnt[t] = 0;
    }
    __syncthreads();

    const int l = blockIdx.x * 256 + t;
    const bool inrange = (l < L_DIM);

    unsigned long long m0 = 0ull, m1 = 0ull;
    if (inrange) {
        const float2 ap = reinterpret_cast<const float2*>(pts)[l];
        for (int n = 0; n < N_DIM; ++n) {
            if (gp[n] <= 0.0f) continue;          // block-uniform skip of padded GTs
            const float4 g = gb[n];
            bool in = (ap.x >= g.x && ap.x <= g.z && ap.y >= g.y && ap.y <= g.w);
            if (n < 64) m0 |= in ? (1ull << n) : 0ull;
            else        m1 |= in ? (1ull << (n - 64)) : 0ull;
        }
        spat[(size_t)b * L_DIM + l] = make_ulonglong2(m0, m1);
        if (l >= 32) {
            // Phase A: local counts (no return-value dependence)
            unsigned long long m = m0;
            while (m) { int n = __ffsll((long long)m) - 1; m &= m - 1; atomicAdd(&lcnt[n], 1); }
            m = m1;
            while (m) { int n = __ffsll((long long)m) - 1; m &= m - 1; atomicAdd(&lcnt[n + 64], 1); }
        }
    }
    __syncthreads();

    // Phase B: one global reservation per (block, n); reuse lcnt as local offset
    if (t < N_DIM) {
        int c = lcnt[t];
        gbase[t] = (c > 0) ? atomicAdd(&cnt[b * N_DIM + t], c) : 0;
        lcnt[t] = 0;
    }
    __syncthreads();

    // Phase C: write pairs at reserved positions
    if (inrange && l >= 32) {
        unsigned long long m = m0;
        while (m) {
            int n = __ffsll((long long)m) - 1; m &= m - 1;
            int pos = gbase[n] + atomicAdd(&lcnt[n], 1);
            if (pos < CAP) bucket[(size_t)(b * N_DIM + n) * CAP + pos] = (unsigned short)l;
        }
        m = m1;
        while (m) {
            int n = __ffsll((long long)m) - 1; m &= m - 1;
            int pos = gbase[n + 64] + atomicAdd(&lcnt[n + 64], 1);
            if (pos < CAP) bucket[(size_t)(b * N_DIM + n + 64) * CAP + pos] = (unsigned short)l;
        }
    }
}

// K_top13: one 256-thread block per (gt n, batch b). Score 32 seeds + bucket
// candidates, per-thread 13-deep sorted reg list, per-wave shuffle head-merge,
// one barrier, single-wave final merge of 4x13 heads; atomicOr posbits.
__global__ __launch_bounds__(256) void k_top13(
    const float* __restrict__ psc, const float* __restrict__ pbox,
    const float* __restrict__ pts, const int* __restrict__ glbl,
    const float* __restrict__ gbox, const float* __restrict__ gpad,
    const int* __restrict__ cnt, const unsigned short* __restrict__ bucket,
    unsigned long long* __restrict__ posbits)
{
    const int n = blockIdx.x, b = blockIdx.y, t = threadIdx.x;
    if (gpad[b * N_DIM + n] <= 0.0f) return;   // padded GT: uniform block exit

    const float g0 = gbox[(b * N_DIM + n) * 4 + 0];
    const float g1 = gbox[(b * N_DIM + n) * 4 + 1];
    const float g2 = gbox[(b * N_DIM + n) * 4 + 2];
    const float g3 = gbox[(b * N_DIM + n) * 4 + 3];
    int lbl = glbl[b * N_DIM + n];
    lbl = min(max(lbl, 0), C_DIM - 1);
    const float* psb = psc + (size_t)b * L_DIM * C_DIM;
    const float* pbb = pbox + (size_t)b * L_DIM * 4;
    const int bn = b * N_DIM + n;
    const int nc = min(cnt[bn], CAP);

    // per-thread top-13, sorted desc, registers only (guarded unrolled insert)
    unsigned long long key[K_TOP];
    #pragma unroll
    for (int k = 0; k < K_TOP; ++k) key[k] = 0ull;

    for (int i = t; i < nc + 32; i += 256) {
        const int l = (i < 32) ? i : (int)bucket[(size_t)bn * CAP + (i - 32)];
        const float2 ap = reinterpret_cast<const float2*>(pts)[l];
        unsigned long long ck = (unsigned long long)(0xFFFF - l);  // s == 0
        if (ap.x >= g0 && ap.x <= g2 && ap.y >= g1 && ap.y <= g3) {
            const float4 pbv = reinterpret_cast<const float4*>(pbb)[l];
            float iou = iou_pair(g0, g1, g2, g3, pbv.x, pbv.y, pbv.z, pbv.w);
            if (iou > 0.0f) {
                float cs = psb[(size_t)l * C_DIM + lbl];
                double d = (double)iou, d2 = d * d;
                ck = make_key((double)cs * (d2 * d2 * d2), l);
            }
        }
        if (ck > key[K_TOP - 1]) {
            #pragma unroll
            for (int k = 0; k < K_TOP; ++k) {
                unsigned long long hi = key[k] > ck ? key[k] : ck;
                unsigned long long lo = key[k] > ck ? ck : key[k];
                key[k] = hi; ck = lo;
            }
        }
    }

    // per-wave head-merge (4 waves), no barriers
    const int lane = t & 63, wid = t >> 6;
    __shared__ unsigned long long wl[4 * K_TOP];
    #pragma unroll 1
    for (int r = 0; r < K_TOP; ++r) {
        unsigned long long best = key[0];
        #pragma unroll
        for (int d = 1; d < 64; d <<= 1) {
            unsigned long long o = __shfl_xor(best, d, 64);
            best = o > best ? o : best;
        }
        if (key[0] == best && best != 0ull) {  // unique keys -> one winner
            #pragma unroll
            for (int k = 0; k < K_TOP - 1; ++k) key[k] = key[k + 1];
            key[K_TOP - 1] = 0ull;
        }
        if (lane == 0) wl[wid * K_TOP + r] = best;
    }
    __syncthreads();
    if (wid != 0) return;

    // single-wave final merge of 52 heads (1 per lane)
    unsigned long long v = (lane < 4 * K_TOP) ? wl[lane] : 0ull;
    #pragma unroll 1
    for (int r = 0; r < K_TOP; ++r) {
        unsigned long long best = v;
        #pragma unroll
        for (int d = 1; d < 64; d <<= 1) {
            unsigned long long o = __shfl_xor(best, d, 64);
            best = o > best ? o : best;
        }
        if (v == best) v = 0ull;               // winner removed (keys unique, best>0)
        if (lane == 0) {
            int win = 0xFFFF - (int)(best & 0xFFFFull);
            atomicOr(&posbits[((size_t)b * L_DIM + win) * 2 + (n >> 6)],
                     1ULL << (n & 63));
        }
    }
}

// K_assign: one thread per anchor. p = posbits & stored-spatial; iou work only
// for positive anchors (pcnt==1: one iou; pcnt>1: rare full 128-iou argmax
// over ALL GTs incl. padded — reference semantics for conflict resolution).
__global__ __launch_bounds__(256) void k_assign(
    const float* __restrict__ psc, const float* __restrict__ pbox,
    const int* __restrict__ glbl, const float* __restrict__ gbox,
    const unsigned long long* __restrict__ posbits,
    const ulonglong2* __restrict__ spat,
    const int* __restrict__ bgp,
    float* __restrict__ out_lab, float* __restrict__ out_box,
    int* __restrict__ fin_out, float* __restrict__ alat,
    float* __restrict__ maxal, float* __restrict__ maxio)
{
    const int b = blockIdx.y, t = threadIdx.x;
    const int l = blockIdx.x * 256 + t;
    __shared__ float4 gb[N_DIM];
    __shared__ int    gl[N_DIM];
    if (t < N_DIM) {
        gb[t] = reinterpret_cast<const float4*>(gbox)[(size_t)b * N_DIM + t];
        gl[t] = glbl[b * N_DIM + t];
    }
    __syncthreads();
    if (l >= L_DIM) return;

    const size_t bl = (size_t)b * L_DIM + l;
    const unsigned long long w0 = posbits[bl * 2 + 0];
    const unsigned long long w1 = posbits[bl * 2 + 1];
    const ulonglong2 sm = spat[bl];
    const unsigned long long p0 = w0 & sm.x, p1 = w1 & sm.y;
    const int pcnt = __popcll(p0) + __popcll(p1);

    int fin = -1;
    if (pcnt == 1) {
        fin = p0 ? (__ffsll(p0) - 1) : (64 + __ffsll(p1) - 1);
    } else if (pcnt > 1) {
        // rare path: best-iou argmax over all 128 GTs (first-max semantics)
        const float4 pb = reinterpret_cast<const float4*>(pbox)[bl];
        float best = -1.0f; int bestn = 0;
        for (int n = 0; n < N_DIM; ++n) {
            float4 g = gb[n];
            float iou = iou_pair(g.x, g.y, g.z, g.w, pb.x, pb.y, pb.z, pb.w);
            if (iou > best) { best = iou; bestn = n; }        // strict > = first-max
        }
        bool posbest = (bestn < 64) ? ((p0 >> bestn) & 1ull) : ((p1 >> (bestn - 64)) & 1ull);
        fin = posbest ? bestn : -1;
    }

    out_lab[bl] = (fin >= 0) ? (float)gl[fin] : (float)bgp[0];
    int gidx = (fin >= 0) ? fin : 0;              // ref gathers boxes with argmax=0 for bg
    reinterpret_cast<float4*>(out_box)[bl] = gb[gidx];
    fin_out[bl] = fin;

    if (fin >= 0) {
        const float4 pb = reinterpret_cast<const float4*>(pbox)[bl];
        float4 g = gb[fin];
        float iou = iou_pair(g.x, g.y, g.z, g.w, pb.x, pb.y, pb.z, pb.w);
        int lb = min(max(gl[fin], 0), C_DIM - 1);
        float cs = psc[bl * C_DIM + lb];
        float al = cs * powf(iou, 6.0f);
        alat[bl] = al;
        // all values >= 0, init 0 -> int-compare == float-compare
        atomicMax((int*)&maxal[b * N_DIM + fin], __float_as_int(al));
        atomicMax((int*)&maxio[b * N_DIM + fin], __float_as_int(iou));
    }
}

// K_out: fused norm + one-hot score fill. 16 anchors per block: threads 0..15
// compute nf/cls into LDS, then 320 coalesced float4 stores (C=80 -> 20/anchor).
__global__ __launch_bounds__(256) void k_out(
    const int* __restrict__ fin_out, const float* __restrict__ alat,
    const float* __restrict__ maxal, const float* __restrict__ maxio,
    const int* __restrict__ glbl,
    float* __restrict__ outs)
{
    const int APB = 16;
    const int a0 = blockIdx.x * APB;
    const int t = threadIdx.x;
    __shared__ float snf[APB];
    __shared__ int   scl[APB];
    if (t < APB) {
        int a = a0 + t;
        float v = 0.0f; int c = -1;
        if (a < B_DIM * L_DIM) {
            int b = a / L_DIM;
            int fin = fin_out[a];
            if (fin >= 0) {
                v = alat[a] / (maxal[b * N_DIM + fin] + EPS_F) * maxio[b * N_DIM + fin];
                c = glbl[b * N_DIM + fin];
            }
        }
        snf[t] = v; scl[t] = c;
    }
    __syncthreads();
    float4* out4 = reinterpret_cast<float4*>(outs);
    for (int j = t; j < APB * 20; j += 256) {
        int ai = j / 20;                      // anchor within block
        int a = a0 + ai;
        if (a >= B_DIM * L_DIM) continue;
        int c0 = (j - ai * 20) * 4;
        float v = snf[ai]; int cl = scl[ai];
        float4 o;
        o.x = (c0 + 0 == cl) ? v : 0.0f;
        o.y = (c0 + 1 == cl) ? v : 0.0f;
        o.z = (c0 + 2 == cl) ? v : 0.0f;
        o.w = (c0 + 3 == cl) ? v : 0.0f;
        out4[(size_t)a * 20 + (j - ai * 20)] = o;
    }
}

extern "C" void kernel_launch(void* const* d_in, const int* in_sizes, int n_in,
                              void* d_out, int out_size, void* d_ws, size_t ws_size,
                              hipStream_t stream)
{
    const float* psc  = (const float*)d_in[0];   // [B,L,C]
    const float* pbox = (const float*)d_in[1];   // [B,L,4]
    const float* pts  = (const float*)d_in[2];   // [1,L,2]
    const int*   glbl = (const int*)d_in[3];     // [B,N,1]
    const float* gbox = (const float*)d_in[4];   // [B,N,4]
    const float* gpad = (const float*)d_in[5];   // [B,N,1]
    const int*   bgp  = (const int*)d_in[6];     // scalar (=C)

    // workspace layout (16-byte aligned blocks)
    const size_t P = (size_t)B_DIM * L_DIM * 2 * sizeof(unsigned long long); // 4,300,800
    char* w = (char*)d_ws;
    unsigned long long* posbits = (unsigned long long*)w;                    // P bytes
    float* maxal = (float*)(w + P);                                          // 4096 B
    float* maxio = (float*)(w + P + 4096);                                   // 4096 B
    int*   cnt   = (int*)  (w + P + 8192);                                   // 4096 B
    ulonglong2* spat = (ulonglong2*)(w + P + 12288);                         // P bytes
    int*   fin   = (int*)  (w + 2 * P + 12288);                              // 1,075,200 B
    float* alat  = (float*)(w + 2 * P + 12288 + 1075200);                    // 1,075,200 B
    unsigned short* bucket = (unsigned short*)(w + 2 * P + 12288 + 2 * 1075200); // 8 MB

    // zero the accumulated regions (posbits + maxal + maxio + cnt); spat is
    // fully overwritten by k_push every call (no re-poison dependence)
    hipMemsetAsync(d_ws, 0, P + 12288, stream);

    float* out_lab = (float*)d_out;                              // [B,L]
    float* out_box = out_lab + (size_t)B_DIM * L_DIM;            // [B,L,4]
    float* out_sc  = out_box + (size_t)B_DIM * L_DIM * 4;        // [B,L,C]

    k_push<<<dim3((L_DIM + 255) / 256, B_DIM), dim3(256), 0, stream>>>(
        pts, gbox, gpad, cnt, bucket, spat);
    k_top13<<<dim3(N_DIM, B_DIM), dim3(256), 0, stream>>>(
        psc, pbox, pts, glbl, gbox, gpad, cnt, bucket, posbits);
    k_assign<<<dim3((L_DIM + 255) / 256, B_DIM), dim3(256), 0, stream>>>(
        psc, pbox, glbl, gbox, posbits, spat, bgp,
        out_lab, out_box, fin, alat, maxal, maxio);
    k_out<<<dim3((B_DIM * L_DIM + 15) / 16), dim3(256), 0, stream>>>(
        fin, alat, maxal, maxio, glbl, out_sc);
}